// Round 14
// baseline (509.926 us; speedup 1.0000x reference)
//
#include <hip/hip_runtime.h>
#include <hip/hip_bf16.h>

// CADTopoEncoder: hetero-GNN (point/edge/face), 2 SAGE layers + LN + pool.
// r14: per layer, ONE fused kernel per dst-type-group (gmm_kernel):
//   gather neighbor means of h (44.8 MB source, L2-friendly) + h_dst copy
//   -> LDS [64 rows x 256 cols] (XOR-swizzled) -> K=256 MFMA against stacked
//   [Wl_a;Wl_b;Wl_c;Wrs] -> +bls, ReLU, residual, LN -> h_next.
// Deletes g_all (121.6 MB) round-trip, t buffer, 11-job GEMM, old gf.
// h double-buffered (hA/hB). CSR build: two-level counting sort (r9/r13).

#define POOL_SPLIT 4
#define NBUCK 49
#define ABLK 4096

typedef __attribute__((ext_vector_type(8))) short bf8_t;   // 8 bf16 in 4 VGPRs
typedef __attribute__((ext_vector_type(4))) float f32x4;

__device__ __forceinline__ ushort f2bf(float f) {
  union { __hip_bfloat16 b; ushort u; } v;
  v.b = __float2bfloat16(f);
  return v.u;
}
__device__ __forceinline__ float u2f(ushort u) {
  union { ushort u; __hip_bfloat16 b; } v;
  v.u = u;
  return __bfloat162float(v.b);
}

// ---------------- prep ---------------------------------------------------------
// fw0: 3 matrices (mlp w2 p/e/f), K=64 fragment order (4096 bf16 each).
// bls: 6x64 summed biases per (layer i, type t): t 0=P(rels0-2) 1=E(rels6-7) 2=F(rels3-5)
// fws: 6 stacked matrices (layer i, type t) 256x64, K=256 fragment order:
//      rows 0:192 = Wl of the type's relations (E: rows128:192 = 0), 192:256 = Wrs sum.
__global__ __launch_bounds__(256) void prep_kernel(
    const float* __restrict__ Wl, const float* __restrict__ Wr,
    const float* __restrict__ bl, const float* __restrict__ w2p,
    const float* __restrict__ w2e, const float* __restrict__ w2f,
    ushort* __restrict__ fw0, float* __restrict__ bls, ushort* __restrict__ fws) {
  int idx = blockIdx.x * blockDim.x + threadIdx.x;
  if (idx < 3 * 4096) {
    int m = idx >> 12, e = idx & 4095;
    int i8 = e >> 3, b = e & 7;
    int lane = i8 & 63, cb = i8 >> 6;
    int ks = cb & 1, ct = cb >> 1;
    int k = ks * 32 + ((lane >> 4) << 3) + b;
    int col = (ct << 4) + (lane & 15);
    const float* w2 = (m == 0) ? w2p : ((m == 1) ? w2e : w2f);
    fw0[idx] = f2bf(w2[(k << 6) + col]);
  } else if (idx < 3 * 4096 + 6 * 64) {
    int j = idx - 3 * 4096;
    int c = j >> 6, e = j & 63;
    int i = c / 3, t = c % 3;
    int rb = (t == 0) ? 0 : ((t == 1) ? 6 : 3);
    int rc = (t == 1) ? 2 : 3;
    float s = 0.f;
    for (int r = 0; r < rc; ++r) s += bl[(i * 8 + rb + r) * 64 + e];
    bls[c * 64 + e] = s;
  } else if (idx < 3 * 4096 + 6 * 64 + 6 * 16384) {
    int j = idx - (3 * 4096 + 6 * 64);
    int m = j >> 14, e = j & 16383;
    int i = m / 3, t = m % 3;
    int i8 = e >> 3, b = e & 7;
    int lane = i8 & 63, cb = i8 >> 6;        // cb = ct*8 + ks
    int ct = cb >> 3, ks = cb & 7;
    int k = ks * 32 + ((lane >> 4) << 3) + b;  // 0..255
    int col = (ct << 4) + (lane & 15);
    int rb = (t == 0) ? 0 : ((t == 1) ? 6 : 3);
    int rc = (t == 1) ? 2 : 3;
    float v;
    if (k < 192) {
      int sec = k >> 6;
      if (sec >= rc) v = 0.f;
      else v = Wl[(size_t)(i * 8 + rb + sec) * 4096 + ((k & 63) << 6) + col];
    } else {
      v = 0.f;
      for (int r = 0; r < rc; ++r)
        v += Wr[(size_t)(i * 8 + rb + r) * 4096 + ((k - 192) << 6) + col];
    }
    fws[(size_t)m * 16384 + e] = f2bf(v);
  }
}

// ---------------- MFMA GEMM K=64 (3 jobs; input-MLP stage 2) -----------------
struct GJob { const ushort* A; const ushort* W; const float* bias; ushort* C; int n; };
struct GJobs3 { GJob j0, j1, j2; };

__global__ __launch_bounds__(256) void gemm3_kernel(GJobs3 js) {
  GJob jb = (blockIdx.y == 0) ? js.j0 : (blockIdx.y == 1) ? js.j1 : js.j2;
  const int n = jb.n;
  const int lane = threadIdx.x & 63;
  const int wid = (blockIdx.x * blockDim.x + threadIdx.x) >> 6;
  const int r0 = wid * 32;
  if (r0 >= n) return;
  bf8_t bw[8];
#pragma unroll
  for (int i = 0; i < 8; ++i)
    bw[i] = *(const bf8_t*)(jb.W + ((i << 6) + lane) * 8);
  const int koff = ((lane >> 4) << 3);
  int ra = r0 + (lane & 15);
  int rb = ra + 16;
  ra = min(ra, n - 1);
  rb = min(rb, n - 1);
  const bf8_t a00 = *(const bf8_t*)(jb.A + (size_t)ra * 64 + koff);
  const bf8_t a01 = *(const bf8_t*)(jb.A + (size_t)ra * 64 + 32 + koff);
  const bf8_t a10 = *(const bf8_t*)(jb.A + (size_t)rb * 64 + koff);
  const bf8_t a11 = *(const bf8_t*)(jb.A + (size_t)rb * 64 + 32 + koff);
  f32x4 acc[8];
#pragma unroll
  for (int i = 0; i < 8; ++i) acc[i] = (f32x4){0.f, 0.f, 0.f, 0.f};
#pragma unroll
  for (int ct = 0; ct < 4; ++ct) {
    acc[ct]     = __builtin_amdgcn_mfma_f32_16x16x32_bf16(a00, bw[ct * 2 + 0], acc[ct], 0, 0, 0);
    acc[ct]     = __builtin_amdgcn_mfma_f32_16x16x32_bf16(a01, bw[ct * 2 + 1], acc[ct], 0, 0, 0);
    acc[4 + ct] = __builtin_amdgcn_mfma_f32_16x16x32_bf16(a10, bw[ct * 2 + 0], acc[4 + ct], 0, 0, 0);
    acc[4 + ct] = __builtin_amdgcn_mfma_f32_16x16x32_bf16(a11, bw[ct * 2 + 1], acc[4 + ct], 0, 0, 0);
  }
  float bv[4];
#pragma unroll
  for (int ct = 0; ct < 4; ++ct) bv[ct] = jb.bias[ct * 16 + (lane & 15)];
  const int rowb = r0 + ((lane >> 4) << 2);
  const int cb = lane & 15;
#pragma unroll
  for (int rt = 0; rt < 2; ++rt) {
#pragma unroll
    for (int q = 0; q < 4; ++q) {
      int row = rowb + rt * 16 + q;
      if (row < n) {
#pragma unroll
        for (int ct = 0; ct < 4; ++ct)
          jb.C[(size_t)row * 64 + ct * 16 + cb] = f2bf(acc[rt * 4 + ct][q] + bv[ct]);
      }
    }
  }
}

// ---------------- mlp stage 1 (3 types in one dispatch) ----------------------
template <int FIN>
__device__ __forceinline__ void mlp1_body(
    const float* __restrict__ x, const float* __restrict__ w1,
    const float* __restrict__ b1, ushort* __restrict__ h1, int n) {
  const int lane = threadIdx.x & 63;
  int wid = (blockIdx.x * blockDim.x + threadIdx.x) >> 6;
  const int nw = (gridDim.x * blockDim.x) >> 6;
  float w1c[FIN];
#pragma unroll
  for (int k = 0; k < FIN; ++k) w1c[k] = w1[k * 64 + lane];
  const float b1v = b1[lane];
  for (int r = wid; r < n; r += nw) {
    float s = b1v;
#pragma unroll
    for (int k = 0; k < FIN; ++k) s = fmaf(x[(size_t)r * FIN + k], w1c[k], s);
    h1[(size_t)r * 64 + lane] = f2bf(fmaxf(s, 0.f));
  }
}

struct MLPJob { const float* x; const float* w1; const float* b1; ushort* o; int n; };
struct MLPack { MLPJob j[3]; };

__global__ __launch_bounds__(256) void mlp1_kernel(MLPack a) {
  if (blockIdx.y == 0)      mlp1_body<3>(a.j[0].x, a.j[0].w1, a.j[0].b1, a.j[0].o, a.j[0].n);
  else if (blockIdx.y == 1) mlp1_body<2>(a.j[1].x, a.j[1].w1, a.j[1].b1, a.j[1].o, a.j[1].n);
  else                      mlp1_body<16>(a.j[2].x, a.j[2].w1, a.j[2].b1, a.j[2].o, a.j[2].n);
}

// ---------------- CSR build: two-level counting sort (packed entries) --------
struct EIPack {
  const int* e0; const int* e1; const int* e2; const int* e3;
  const int* e4; const int* e5; const int* e6; const int* e7;
  int b0, b1, b2, b3, b4, b5, b6, b7;
};

__device__ __forceinline__ void ei_sel(const EIPack& t, int r, const int*& ei, int& b) {
  switch (r) {
    case 0: ei = t.e0; b = t.b0; break;
    case 1: ei = t.e1; b = t.b1; break;
    case 2: ei = t.e2; b = t.b2; break;
    case 3: ei = t.e3; b = t.b3; break;
    case 4: ei = t.e4; b = t.b4; break;
    case 5: ei = t.e5; b = t.b5; break;
    case 6: ei = t.e6; b = t.b6; break;
    default: ei = t.e7; b = t.b7; break;
  }
}

__device__ __forceinline__ int rel_shift(int rel) {
  return rel < 3 ? 12 : (rel < 6 ? 10 : 11);  // P:4096, F:1024, E:2048 dsts/bucket
}

__global__ __launch_bounds__(256) void binA1_kernel(EIPack t, int* __restrict__ counts,
                                                    int E, int nblk) {
  __shared__ int hist[NBUCK];
  int rel = blockIdx.x % 8, blk = blockIdx.x / 8;
  const int* ei; int bb;
  ei_sel(t, rel, ei, bb);
  int shift = rel_shift(rel);
  for (int i = threadIdx.x; i < NBUCK; i += 256) hist[i] = 0;
  __syncthreads();
  int e0 = blk * ABLK;
  for (int i = threadIdx.x; i < ABLK; i += 256) {
    int e = e0 + i;
    if (e < E) {
      int d = __builtin_nontemporal_load(ei + E + e);
      atomicAdd(&hist[d >> shift], 1);
    }
  }
  __syncthreads();
  for (int i = threadIdx.x; i < NBUCK; i += 256)
    counts[(rel * NBUCK + i) * nblk + blk] = hist[i];
}

__global__ __launch_bounds__(256) void binA2_kernel(EIPack t, const int* __restrict__ coff,
                                                    int* __restrict__ bed,
                                                    int E, int nblk) {
  __shared__ int cur[NBUCK];
  int rel = blockIdx.x % 8, blk = blockIdx.x / 8;
  const int* ei; int bb;
  ei_sel(t, rel, ei, bb);
  int shift = rel_shift(rel);
  int lmask = (1 << shift) - 1;
  for (int i = threadIdx.x; i < NBUCK; i += 256)
    cur[i] = coff[(rel * NBUCK + i) * nblk + blk];
  __syncthreads();
  int e0 = blk * ABLK;
  for (int i = threadIdx.x; i < ABLK; i += 256) {
    int e = e0 + i;
    if (e < E) {
      int s = __builtin_nontemporal_load(ei + e);
      int d = __builtin_nontemporal_load(ei + E + e);
      int p = atomicAdd(&cur[d >> shift], 1);
      bed[p] = ((d & lmask) << 18) | s;
    }
  }
}

__global__ __launch_bounds__(256) void binB_kernel(const int* __restrict__ coff,
                                                   const int* __restrict__ bed,
                                                   int* __restrict__ off,
                                                   int* __restrict__ srcs,
                                                   int nblk, int NP_, int NF_, int NE_,
                                                   int Etot) {
  __shared__ int hist[4096];
  __shared__ int wsum[4];
  int gb = blockIdx.x;                    // 0..8*NBUCK-1
  int rel = gb / NBUCK, b = gb % NBUCK;
  int shift = rel_shift(rel);
  int D = 1 << shift;
  int ndst_r = rel < 3 ? NP_ : (rel < 6 ? NF_ : NE_);
  int rbase = rel < 3 ? rel * NP_
            : (rel < 6 ? 3 * NP_ + (rel - 3) * NF_
                       : 3 * NP_ + 3 * NF_ + (rel - 6) * NE_);
  int d0 = b << shift;
  int Dl = min(D, ndst_r - d0);
  int ebase = coff[gb * nblk];
  int eend  = coff[(gb + 1) * nblk];
  for (int i = threadIdx.x; i < D; i += 256) hist[i] = 0;
  __syncthreads();
  for (int e = ebase + threadIdx.x; e < eend; e += 256)
    atomicAdd(&hist[bed[e] >> 18], 1);
  __syncthreads();
  const int PT = D >> 8;
  int tbase = threadIdx.x * PT;
  int ts = 0;
  for (int k = 0; k < PT; ++k) ts += hist[tbase + k];
  int lane = threadIdx.x & 63, w = threadIdx.x >> 6;
  int x = ts;
#pragma unroll
  for (int dd = 1; dd < 64; dd <<= 1) {
    int y = __shfl_up(x, dd, 64);
    if (lane >= dd) x += y;
  }
  if (lane == 63) wsum[w] = x;
  __syncthreads();
  int woff = 0;
#pragma unroll
  for (int k = 0; k < 4; ++k)
    if (k < w) woff += wsum[k];
  int pos = woff + x - ts;
  for (int k = 0; k < PT; ++k) {
    int c = hist[tbase + k];
    hist[tbase + k] = pos;
    if (tbase + k < Dl) off[rbase + d0 + tbase + k] = ebase + pos;
    pos += c;
  }
  __syncthreads();
  for (int e = ebase + threadIdx.x; e < eend; e += 256) {
    int w_ = bed[e];
    int p = atomicAdd(&hist[w_ >> 18], 1);
    srcs[ebase + p] = w_ & 0x3FFFF;
  }
  if (gb == 0 && threadIdx.x == 0)
    off[3 * NP_ + 3 * NF_ + 2 * NE_] = Etot;
}

__global__ __launch_bounds__(256) void scan1_kernel(const int* __restrict__ cnt,
                                                    int* __restrict__ part, int n) {
  __shared__ int wt[4];
  int base = blockIdx.x * 1024;
  int t = 0;
  for (int i = threadIdx.x; i < 1024; i += 256) {
    int idx = base + i;
    if (idx < n) t += cnt[idx];
  }
#pragma unroll
  for (int d = 32; d > 0; d >>= 1) t += __shfl_xor(t, d, 64);
  if ((threadIdx.x & 63) == 0) wt[threadIdx.x >> 6] = t;
  __syncthreads();
  if (threadIdx.x == 0) part[blockIdx.x] = wt[0] + wt[1] + wt[2] + wt[3];
}

__global__ __launch_bounds__(1024) void scan2_kernel(int* __restrict__ part,
                                                     int* __restrict__ off, int nb,
                                                     int n, int total) {
  __shared__ int lds[1024];
  int tid = threadIdx.x;
  int v = (tid < nb) ? part[tid] : 0;
  lds[tid] = v;
  __syncthreads();
  for (int d = 1; d < 1024; d <<= 1) {
    int y = (tid >= d) ? lds[tid - d] : 0;
    __syncthreads();
    lds[tid] += y;
    __syncthreads();
  }
  if (tid < nb) part[tid] = lds[tid] - v;  // exclusive
  if (tid == 0) off[n] = total;
}

__global__ __launch_bounds__(256) void scan3_kernel(const int* cnt,
                                                    const int* __restrict__ part,
                                                    int* __restrict__ out, int n) {
  __shared__ int wt[4];
  int base = blockIdx.x * 1024 + threadIdx.x * 4;
  int c[4];
#pragma unroll
  for (int k = 0; k < 4; ++k) {
    int idx = base + k;
    c[k] = (idx < n) ? cnt[idx] : 0;
  }
  int t = c[0] + c[1] + c[2] + c[3];
  int lane = threadIdx.x & 63, w = threadIdx.x >> 6;
  int x = t;
#pragma unroll
  for (int d = 1; d < 64; d <<= 1) {
    int y = __shfl_up(x, d, 64);
    if (lane >= d) x += y;
  }
  int ex = x - t;
  if (lane == 63) wt[w] = x;
  __syncthreads();
  int woff = 0;
#pragma unroll
  for (int k = 0; k < 4; ++k)
    if (k < w) woff += wt[k];
  int pos = part[blockIdx.x] + woff + ex;
#pragma unroll
  for (int k = 0; k < 4; ++k) {
    int idx = base + k;
    if (idx < n) out[idx] = pos;
    pos += c[k];
  }
}

// ---- fused layer kernel: gather means -> LDS[64x256] -> K=256 MFMA -> LN ----
struct GMType {
  const ushort* s0; const ushort* s1; const ushort* s2;   // gather sources
  const ushort* hd;  ushort* hn;                           // h in / h out
  const ushort* ws;                                        // stacked weights (frag order)
  const float* bls; const float* lng; const float* lnb;
  int b0, b1, b2, nrel, ndst;
};
struct GMPack { GMType t[3]; };

__device__ __forceinline__ void gm_gather(const ushort* __restrict__ g,
    const int* __restrict__ srcs, int e0, int e1, int l8, float t8[8]) {
#pragma unroll
  for (int c = 0; c < 8; ++c) t8[c] = 0.f;
  int j = e0;
  for (; j + 2 <= e1; j += 2) {
    int s0 = srcs[j], s1 = srcs[j + 1];
    bf8_t v0 = *(const bf8_t*)(g + (size_t)s0 * 64 + l8 * 8);
    bf8_t v1 = *(const bf8_t*)(g + (size_t)s1 * 64 + l8 * 8);
#pragma unroll
    for (int c = 0; c < 8; ++c) t8[c] += u2f((ushort)v0[c]) + u2f((ushort)v1[c]);
  }
  if (j < e1) {
    int s = srcs[j];
    bf8_t v = *(const bf8_t*)(g + (size_t)s * 64 + l8 * 8);
#pragma unroll
    for (int c = 0; c < 8; ++c) t8[c] += u2f((ushort)v[c]);
  }
  float inv = 1.f / fmaxf((float)(e1 - e0), 1.f);
#pragma unroll
  for (int c = 0; c < 8; ++c) t8[c] *= inv;
}

__global__ __launch_bounds__(256) void gmm_kernel(GMPack pk, const int* __restrict__ srcs,
                                                  const int* __restrict__ off) {
  GMType ty = (blockIdx.y == 0) ? pk.t[0] : (blockIdx.y == 1) ? pk.t[1] : pk.t[2];
  const int rowbase = blockIdx.x * 64;
  if (rowbase >= ty.ndst) return;
  __shared__ ushort Ml[64 * 256];   // 32 KB, 16B chunks swizzled: c' = c ^ (row&7)

  // ---- gather phase: 32 groups x 8 lanes; group handles 2 rows x 4 sections --
  const int grp = threadIdx.x >> 3;
  const int l8 = threadIdx.x & 7;
#pragma unroll
  for (int rr = 0; rr < 2; ++rr) {
    int lr = grp * 2 + rr;
    int d = rowbase + lr;
    int sw = lr & 7;
    bf8_t zero = {};
    if (d < ty.ndst) {
      float t8[8];
      bf8_t pkd;
      // section 0
      gm_gather(ty.s0, srcs, off[ty.b0 + d], off[ty.b0 + d + 1], l8, t8);
#pragma unroll
      for (int c = 0; c < 8; ++c) pkd[c] = (short)f2bf(t8[c]);
      *(bf8_t*)(Ml + lr * 256 + ((0 * 8 + l8) ^ sw) * 8) = pkd;
      // section 1
      gm_gather(ty.s1, srcs, off[ty.b1 + d], off[ty.b1 + d + 1], l8, t8);
#pragma unroll
      for (int c = 0; c < 8; ++c) pkd[c] = (short)f2bf(t8[c]);
      *(bf8_t*)(Ml + lr * 256 + ((1 * 8 + l8) ^ sw) * 8) = pkd;
      // section 2 (zero for 2-relation types)
      if (ty.nrel > 2) {
        gm_gather(ty.s2, srcs, off[ty.b2 + d], off[ty.b2 + d + 1], l8, t8);
#pragma unroll
        for (int c = 0; c < 8; ++c) pkd[c] = (short)f2bf(t8[c]);
        *(bf8_t*)(Ml + lr * 256 + ((2 * 8 + l8) ^ sw) * 8) = pkd;
      } else {
        *(bf8_t*)(Ml + lr * 256 + ((2 * 8 + l8) ^ sw) * 8) = zero;
      }
      // section 3: h_dst copy
      *(bf8_t*)(Ml + lr * 256 + ((3 * 8 + l8) ^ sw) * 8) =
          *(const bf8_t*)(ty.hd + (size_t)d * 64 + l8 * 8);
    } else {
#pragma unroll
      for (int s = 0; s < 4; ++s)
        *(bf8_t*)(Ml + lr * 256 + ((s * 8 + l8) ^ sw) * 8) = zero;
    }
  }
  __syncthreads();

  // ---- MFMA phase: wave w -> rows w*16..w*16+15, K=256 (8 k-steps) ----------
  const int lane = threadIdx.x & 63;
  const int w = threadIdx.x >> 6;
  const int lr = w * 16 + (lane & 15);
  f32x4 acc[4];
#pragma unroll
  for (int i = 0; i < 4; ++i) acc[i] = (f32x4){0.f, 0.f, 0.f, 0.f};
#pragma unroll
  for (int ks = 0; ks < 8; ++ks) {
    int c8 = ks * 4 + (lane >> 4);
    bf8_t af = *(const bf8_t*)(Ml + lr * 256 + (c8 ^ (lr & 7)) * 8);
#pragma unroll
    for (int ct = 0; ct < 4; ++ct) {
      bf8_t bf = *(const bf8_t*)(ty.ws + ((size_t)(ct * 8 + ks) * 64 + lane) * 8);
      acc[ct] = __builtin_amdgcn_mfma_f32_16x16x32_bf16(af, bf, acc[ct], 0, 0, 0);
    }
  }

  // ---- epilogue: +bls, ReLU, residual, LN, store h_next ---------------------
  const int cl = lane & 15;
  float blv[4], ggv[4], bbv[4];
#pragma unroll
  for (int ct = 0; ct < 4; ++ct) {
    blv[ct] = ty.bls[ct * 16 + cl];
    ggv[ct] = ty.lng[ct * 16 + cl];
    bbv[ct] = ty.lnb[ct * 16 + cl];
  }
#pragma unroll
  for (int q = 0; q < 4; ++q) {
    int d = rowbase + w * 16 + ((lane >> 4) << 2) + q;
    if (d < ty.ndst) {
      float v[4];
      float s = 0.f;
#pragma unroll
      for (int ct = 0; ct < 4; ++ct) {
        float hv = u2f(ty.hd[(size_t)d * 64 + ct * 16 + cl]);
        float x = hv + fmaxf(acc[ct][q] + blv[ct], 0.f);
        v[ct] = x;
        s += x;
      }
      s += __shfl_xor(s, 1, 64);
      s += __shfl_xor(s, 2, 64);
      s += __shfl_xor(s, 4, 64);
      s += __shfl_xor(s, 8, 64);
      float m = s * (1.f / 64.f);
      float vs = 0.f;
#pragma unroll
      for (int ct = 0; ct < 4; ++ct) {
        float dd = v[ct] - m;
        vs += dd * dd;
      }
      vs += __shfl_xor(vs, 1, 64);
      vs += __shfl_xor(vs, 2, 64);
      vs += __shfl_xor(vs, 4, 64);
      vs += __shfl_xor(vs, 8, 64);
      float rstd = rsqrtf(vs * (1.f / 64.f) + 1e-5f);
#pragma unroll
      for (int ct = 0; ct < 4; ++ct)
        ty.hn[(size_t)d * 64 + ct * 16 + cl] = f2bf((v[ct] - m) * rstd * ggv[ct] + bbv[ct]);
    }
  }
}

// ---------------- pool: 256 threads, bf8 loads, wave shfl reduce -------------
struct PoolArgs {
  const ushort* h0; const ushort* h1; const ushort* h2;
  const int* b0; const int* b1; const int* b2;
  int n0, n1, n2;
};

__global__ __launch_bounds__(256) void pool_kernel(PoolArgs a, float* __restrict__ out) {
  int ty = blockIdx.y;
  const ushort* h = (ty == 0) ? a.h0 : (ty == 1) ? a.h1 : a.h2;
  const int* batch = (ty == 0) ? a.b0 : (ty == 1) ? a.b1 : a.b2;
  int n = (ty == 0) ? a.n0 : (ty == 1) ? a.n1 : a.n2;
  int col_base = ty * 64;
  int gph = blockIdx.x >> 2;             // POOL_SPLIT = 4
  int s = blockIdx.x & 3;
  int lo = 0, hi = n;
  while (lo < hi) { int mid = (lo + hi) >> 1; if (batch[mid] < gph) lo = mid + 1; else hi = mid; }
  int beg = lo;
  hi = n;
  while (lo < hi) { int mid = (lo + hi) >> 1; if (batch[mid] < gph + 1) lo = mid + 1; else hi = mid; }
  int end = lo;
  int cnt = end - beg;
  if (cnt <= 0) return;
  int per = (cnt + POOL_SPLIT - 1) >> 2;
  int rb = beg + s * per;
  int re = min(rb + per, end);
  if (rb >= re) return;
  const int l8 = threadIdx.x & 7;
  const int grp = threadIdx.x >> 3;
  float o[8];
#pragma unroll
  for (int c = 0; c < 8; ++c) o[c] = 0.f;
  for (int r = rb + grp; r < re; r += 32) {
    bf8_t v = *(const bf8_t*)(h + (size_t)r * 64 + l8 * 8);
#pragma unroll
    for (int c = 0; c < 8; ++c) o[c] += u2f((ushort)v[c]);
  }
#pragma unroll
  for (int c = 0; c < 8; ++c) {
    o[c] += __shfl_xor(o[c], 8, 64);
    o[c] += __shfl_xor(o[c], 16, 64);
    o[c] += __shfl_xor(o[c], 32, 64);
  }
  if ((threadIdx.x & 56) == 0) {
#pragma unroll
    for (int c = 0; c < 8; ++c)
      unsafeAtomicAdd(out + gph * 192 + col_base + l8 * 8 + c, o[c]);
  }
}

__global__ __launch_bounds__(256) void pool_scale_kernel(
    float* __restrict__ out, const int* __restrict__ bp,
    const int* __restrict__ be, const int* __restrict__ bf,
    int np, int ne, int nf) {
  int idx = blockIdx.x * blockDim.x + threadIdx.x;
  if (idx >= 64 * 192) return;
  int gph = idx / 192, col = idx % 192;
  const int* b;
  int n;
  if (col < 64) { b = bp; n = np; }
  else if (col < 128) { b = be; n = ne; }
  else { b = bf; n = nf; }
  int lo = 0, hi = n;
  while (lo < hi) { int mid = (lo + hi) >> 1; if (b[mid] < gph) lo = mid + 1; else hi = mid; }
  int beg = lo;
  hi = n;
  while (lo < hi) { int mid = (lo + hi) >> 1; if (b[mid] < gph + 1) lo = mid + 1; else hi = mid; }
  int cnt = lo - beg;
  out[idx] = out[idx] / fmaxf((float)cnt, 1.f);
}

extern "C" void kernel_launch(void* const* d_in, const int* in_sizes, int n_in,
                              void* d_out, int out_size, void* d_ws, size_t ws_size,
                              hipStream_t stream) {
  const float* point_x = (const float*)d_in[0];
  const float* edge_x  = (const float*)d_in[1];
  const float* face_x  = (const float*)d_in[2];
  const int* bp = (const int*)d_in[3];
  const int* be = (const int*)d_in[4];
  const int* bf = (const int*)d_in[5];
  const int NP = in_sizes[3], NE = in_sizes[4], NF = in_sizes[5];
  const int Eg = in_sizes[6] / 2;

  const float* Wl  = (const float*)d_in[26];
  const float* blp = (const float*)d_in[27];
  const float* Wr  = (const float*)d_in[28];
  const float* lng = (const float*)d_in[29];
  const float* lnb = (const float*)d_in[30];

  // relations: 0 pp 1 fp 2 ep (dst P) | 3 pf 4 ef 5 ff (dst F) | 6 pe 7 fe (dst E)
  int ndst[8] = {NP, NP, NP, NF, NF, NF, NE, NE};
  int base[8];
  base[0] = 0;
  for (int r = 1; r < 8; ++r) base[r] = base[r - 1] + ndst[r - 1];
  const int NDSUM = 3 * NP + 3 * NF + 2 * NE;

  // ---- workspace layout (~110 MB) ----
  char* p = (char*)d_ws;
  ushort* hA = (ushort*)p; p += (size_t)(NP + NE + NF) * 64 * 2;   // 44.8 MB
  ushort* hB = (ushort*)p; p += (size_t)(NP + NE + NF) * 64 * 2;   // 44.8 MB
  ushort* fw0 = (ushort*)p; p += (size_t)3 * 4096 * 2;
  float* bls = (float*)p; p += 6 * 64 * 4;
  ushort* fws = (ushort*)p; p += (size_t)6 * 16384 * 2;
  int* srcs = (int*)p; p += (size_t)8 * Eg * 4;                     // 16 MB
  int* off = (int*)p; p += (size_t)(NDSUM + 1) * 4;
  const int nblk = (Eg + ABLK - 1) / ABLK;
  const int NCNT = 8 * NBUCK * nblk;
  int* counts = (int*)p; p += (size_t)NCNT * 4;
  int* coff = (int*)p; p += (size_t)(NCNT + 1) * 4;
  int* part = (int*)p; p += 4096;
  int* bed = (int*)hB;   // 16 MB alias; CSR build completes before hB is written

  ushort* h_[2][3];
  h_[0][0] = hA; h_[0][1] = hA + (size_t)NP * 64; h_[0][2] = hA + (size_t)(NP + NE) * 64;
  h_[1][0] = hB; h_[1][1] = hB + (size_t)NP * 64; h_[1][2] = hB + (size_t)(NP + NE) * 64;

  const int* ei[8] = {(const int*)d_in[6],  (const int*)d_in[7],
                      (const int*)d_in[8],  (const int*)d_in[9],
                      (const int*)d_in[10], (const int*)d_in[11],
                      (const int*)d_in[12], (const int*)d_in[13]};
  EIPack ep;
  ep.e0 = ei[0]; ep.e1 = ei[1]; ep.e2 = ei[2]; ep.e3 = ei[3];
  ep.e4 = ei[4]; ep.e5 = ei[5]; ep.e6 = ei[6]; ep.e7 = ei[7];
  ep.b0 = base[0]; ep.b1 = base[1]; ep.b2 = base[2]; ep.b3 = base[3];
  ep.b4 = base[4]; ep.b5 = base[5]; ep.b6 = base[6]; ep.b7 = base[7];

  // ---- CSR build (bed aliases hB; finishes before mlp1 writes hB) ----
  binA1_kernel<<<8 * nblk, 256, 0, stream>>>(ep, counts, Eg, nblk);
  const int nb = (NCNT + 1023) / 1024;
  scan1_kernel<<<nb, 256, 0, stream>>>(counts, part, NCNT);
  scan2_kernel<<<1, 1024, 0, stream>>>(part, coff, nb, NCNT, 8 * Eg);
  scan3_kernel<<<nb, 256, 0, stream>>>(counts, part, coff, NCNT);
  binA2_kernel<<<8 * nblk, 256, 0, stream>>>(ep, coff, bed, Eg, nblk);
  binB_kernel<<<8 * NBUCK, 256, 0, stream>>>(coff, bed, off, srcs,
                                             nblk, NP, NF, NE, 8 * Eg);

  // ---- weight prep ----
  prep_kernel<<<(3 * 4096 + 6 * 64 + 6 * 16384 + 255) / 256, 256, 0, stream>>>(
      Wl, Wr, blp, (const float*)d_in[16], (const float*)d_in[20],
      (const float*)d_in[24], fw0, bls, fws);

  // ---- input MLPs: stage1 into hB scratch, stage2 K=64 MFMA -> hA ----
  MLPack ma;
  ma.j[0] = {point_x, (const float*)d_in[14], (const float*)d_in[15], h_[1][0], NP};
  ma.j[1] = {edge_x,  (const float*)d_in[18], (const float*)d_in[19], h_[1][1], NE};
  ma.j[2] = {face_x,  (const float*)d_in[22], (const float*)d_in[23], h_[1][2], NF};
  mlp1_kernel<<<dim3(512, 3), 256, 0, stream>>>(ma);

  GJobs3 init;
  init.j0 = {h_[1][0], fw0 + 0 * 4096, (const float*)d_in[17], h_[0][0], NP};
  init.j1 = {h_[1][1], fw0 + 1 * 4096, (const float*)d_in[21], h_[0][1], NE};
  init.j2 = {h_[1][2], fw0 + 2 * 4096, (const float*)d_in[25], h_[0][2], NF};
  gemm3_kernel<<<dim3(((NP + 31) / 32 + 3) / 4, 3), 256, 0, stream>>>(init);

  // ---- 2 hetero-SAGE layers: ONE fused dispatch each ----
  const int gmx = (NP + 63) / 64;
  int cs = 0;
  for (int i = 0; i < 2; ++i) {
    int ns = cs ^ 1;
    ushort* hp_ = h_[cs][0];
    ushort* he_ = h_[cs][1];
    ushort* hf_ = h_[cs][2];
    GMPack pk;
    // P (t=0): rels 0(src p),1(src f),2(src e)
    pk.t[0] = {hp_, hf_, he_, hp_, h_[ns][0], fws + (size_t)(i * 3 + 0) * 16384,
               bls + (i * 3 + 0) * 64, lng + (i * 3 + 0) * 64, lnb + (i * 3 + 0) * 64,
               base[0], base[1], base[2], 3, NP};
    // F (t=2): rels 3(src p),4(src e),5(src f)
    pk.t[1] = {hp_, he_, hf_, hf_, h_[ns][2], fws + (size_t)(i * 3 + 2) * 16384,
               bls + (i * 3 + 2) * 64, lng + (i * 3 + 2) * 64, lnb + (i * 3 + 2) * 64,
               base[3], base[4], base[5], 3, NF};
    // E (t=1): rels 6(src p),7(src f)
    pk.t[2] = {hp_, hf_, nullptr, he_, h_[ns][1], fws + (size_t)(i * 3 + 1) * 16384,
               bls + (i * 3 + 1) * 64, lng + (i * 3 + 1) * 64, lnb + (i * 3 + 1) * 64,
               base[6], base[7], 0, 2, NE};
    gmm_kernel<<<dim3(gmx, 3), 256, 0, stream>>>(pk, srcs, off);
    cs = ns;
  }

  // ---- pool + scale ----
  float* out = (float*)d_out;
  hipMemsetAsync(out, 0, (size_t)out_size * sizeof(float), stream);
  PoolArgs pa;
  pa.h0 = h_[cs][0]; pa.h1 = h_[cs][1]; pa.h2 = h_[cs][2];
  pa.b0 = bp; pa.b1 = be; pa.b2 = bf;
  pa.n0 = NP; pa.n1 = NE; pa.n2 = NF;
  pool_kernel<<<dim3(64 * POOL_SPLIT, 3), 256, 0, stream>>>(pa, out);
  pool_scale_kernel<<<(64 * 192 + 255) / 256, 256, 0, stream>>>(out, bp, be, bf, NP, NE, NF);
}

// Round 15
// 451.827 us; speedup vs baseline: 1.1286x; 1.1286x over previous
//
#include <hip/hip_runtime.h>
#include <hip/hip_bf16.h>

// CADTopoEncoder: hetero-GNN (point/edge/face), 2 SAGE layers + LN + pool.
// r15: per layer TWO dispatches:
//  1) mean_kernel: independent 8-lane group per (dst,relation), gathers h rows
//     (44.8MB source, cache-resident) -> bf16 mean rows in mg (barrier-free,
//     r13-proven gather structure).
//  2) gemmln_kernel: K=256 MFMA, A=[mean_a|mean_b|mean_c|h_dst] read straight
//     from global (no LDS), + bias/ReLU/residual/LN epilogue -> h_next.
// CSR build: two-level counting sort (r9/r13). h double-buffered.

#define POOL_SPLIT 4
#define NBUCK 49
#define ABLK 4096

typedef __attribute__((ext_vector_type(8))) short bf8_t;   // 8 bf16 in 4 VGPRs
typedef __attribute__((ext_vector_type(4))) float f32x4;

__device__ __forceinline__ ushort f2bf(float f) {
  union { __hip_bfloat16 b; ushort u; } v;
  v.b = __float2bfloat16(f);
  return v.u;
}
__device__ __forceinline__ float u2f(ushort u) {
  union { ushort u; __hip_bfloat16 b; } v;
  v.u = u;
  return __bfloat162float(v.b);
}

// ---------------- prep ---------------------------------------------------------
// fw0: 3 matrices (mlp w2 p/e/f), K=64 fragment order.
// bls: 6x64 summed biases per (layer i, type t): t 0=P 1=E 2=F.
// fws: 6 stacked 256x64 matrices (layer, type), K=256 fragment order:
//      k rows 0:192 = Wl sections (E: 128:192 zero), 192:256 = Wrs sum.
__global__ __launch_bounds__(256) void prep_kernel(
    const float* __restrict__ Wl, const float* __restrict__ Wr,
    const float* __restrict__ bl, const float* __restrict__ w2p,
    const float* __restrict__ w2e, const float* __restrict__ w2f,
    ushort* __restrict__ fw0, float* __restrict__ bls, ushort* __restrict__ fws) {
  int idx = blockIdx.x * blockDim.x + threadIdx.x;
  if (idx < 3 * 4096) {
    int m = idx >> 12, e = idx & 4095;
    int i8 = e >> 3, b = e & 7;
    int lane = i8 & 63, cb = i8 >> 6;
    int ks = cb & 1, ct = cb >> 1;
    int k = ks * 32 + ((lane >> 4) << 3) + b;
    int col = (ct << 4) + (lane & 15);
    const float* w2 = (m == 0) ? w2p : ((m == 1) ? w2e : w2f);
    fw0[idx] = f2bf(w2[(k << 6) + col]);
  } else if (idx < 3 * 4096 + 6 * 64) {
    int j = idx - 3 * 4096;
    int c = j >> 6, e = j & 63;
    int i = c / 3, t = c % 3;
    int rb = (t == 0) ? 0 : ((t == 1) ? 6 : 3);
    int rc = (t == 1) ? 2 : 3;
    float s = 0.f;
    for (int r = 0; r < rc; ++r) s += bl[(i * 8 + rb + r) * 64 + e];
    bls[c * 64 + e] = s;
  } else if (idx < 3 * 4096 + 6 * 64 + 6 * 16384) {
    int j = idx - (3 * 4096 + 6 * 64);
    int m = j >> 14, e = j & 16383;
    int i = m / 3, t = m % 3;
    int i8 = e >> 3, b = e & 7;
    int lane = i8 & 63, cb = i8 >> 6;        // cb = ct*8 + ks
    int ct = cb >> 3, ks = cb & 7;
    int k = ks * 32 + ((lane >> 4) << 3) + b;  // 0..255
    int col = (ct << 4) + (lane & 15);
    int rb = (t == 0) ? 0 : ((t == 1) ? 6 : 3);
    int rc = (t == 1) ? 2 : 3;
    float v;
    if (k < 192) {
      int sec = k >> 6;
      if (sec >= rc) v = 0.f;
      else v = Wl[(size_t)(i * 8 + rb + sec) * 4096 + ((k & 63) << 6) + col];
    } else {
      v = 0.f;
      for (int r = 0; r < rc; ++r)
        v += Wr[(size_t)(i * 8 + rb + r) * 4096 + ((k - 192) << 6) + col];
    }
    fws[(size_t)m * 16384 + e] = f2bf(v);
  }
}

// ---------------- MFMA GEMM K=64 (3 jobs; input-MLP stage 2) -----------------
struct GJob { const ushort* A; const ushort* W; const float* bias; ushort* C; int n; };
struct GJobs3 { GJob j0, j1, j2; };

__global__ __launch_bounds__(256) void gemm3_kernel(GJobs3 js) {
  GJob jb = (blockIdx.y == 0) ? js.j0 : (blockIdx.y == 1) ? js.j1 : js.j2;
  const int n = jb.n;
  const int lane = threadIdx.x & 63;
  const int wid = (blockIdx.x * blockDim.x + threadIdx.x) >> 6;
  const int r0 = wid * 32;
  if (r0 >= n) return;
  bf8_t bw[8];
#pragma unroll
  for (int i = 0; i < 8; ++i)
    bw[i] = *(const bf8_t*)(jb.W + ((i << 6) + lane) * 8);
  const int koff = ((lane >> 4) << 3);
  int ra = r0 + (lane & 15);
  int rb = ra + 16;
  ra = min(ra, n - 1);
  rb = min(rb, n - 1);
  const bf8_t a00 = *(const bf8_t*)(jb.A + (size_t)ra * 64 + koff);
  const bf8_t a01 = *(const bf8_t*)(jb.A + (size_t)ra * 64 + 32 + koff);
  const bf8_t a10 = *(const bf8_t*)(jb.A + (size_t)rb * 64 + koff);
  const bf8_t a11 = *(const bf8_t*)(jb.A + (size_t)rb * 64 + 32 + koff);
  f32x4 acc[8];
#pragma unroll
  for (int i = 0; i < 8; ++i) acc[i] = (f32x4){0.f, 0.f, 0.f, 0.f};
#pragma unroll
  for (int ct = 0; ct < 4; ++ct) {
    acc[ct]     = __builtin_amdgcn_mfma_f32_16x16x32_bf16(a00, bw[ct * 2 + 0], acc[ct], 0, 0, 0);
    acc[ct]     = __builtin_amdgcn_mfma_f32_16x16x32_bf16(a01, bw[ct * 2 + 1], acc[ct], 0, 0, 0);
    acc[4 + ct] = __builtin_amdgcn_mfma_f32_16x16x32_bf16(a10, bw[ct * 2 + 0], acc[4 + ct], 0, 0, 0);
    acc[4 + ct] = __builtin_amdgcn_mfma_f32_16x16x32_bf16(a11, bw[ct * 2 + 1], acc[4 + ct], 0, 0, 0);
  }
  float bv[4];
#pragma unroll
  for (int ct = 0; ct < 4; ++ct) bv[ct] = jb.bias[ct * 16 + (lane & 15)];
  const int rowb = r0 + ((lane >> 4) << 2);
  const int cb = lane & 15;
#pragma unroll
  for (int rt = 0; rt < 2; ++rt) {
#pragma unroll
    for (int q = 0; q < 4; ++q) {
      int row = rowb + rt * 16 + q;
      if (row < n) {
#pragma unroll
        for (int ct = 0; ct < 4; ++ct)
          jb.C[(size_t)row * 64 + ct * 16 + cb] = f2bf(acc[rt * 4 + ct][q] + bv[ct]);
      }
    }
  }
}

// ---------------- mlp stage 1 (3 types in one dispatch) ----------------------
template <int FIN>
__device__ __forceinline__ void mlp1_body(
    const float* __restrict__ x, const float* __restrict__ w1,
    const float* __restrict__ b1, ushort* __restrict__ h1, int n) {
  const int lane = threadIdx.x & 63;
  int wid = (blockIdx.x * blockDim.x + threadIdx.x) >> 6;
  const int nw = (gridDim.x * blockDim.x) >> 6;
  float w1c[FIN];
#pragma unroll
  for (int k = 0; k < FIN; ++k) w1c[k] = w1[k * 64 + lane];
  const float b1v = b1[lane];
  for (int r = wid; r < n; r += nw) {
    float s = b1v;
#pragma unroll
    for (int k = 0; k < FIN; ++k) s = fmaf(x[(size_t)r * FIN + k], w1c[k], s);
    h1[(size_t)r * 64 + lane] = f2bf(fmaxf(s, 0.f));
  }
}

struct MLPJob { const float* x; const float* w1; const float* b1; ushort* o; int n; };
struct MLPack { MLPJob j[3]; };

__global__ __launch_bounds__(256) void mlp1_kernel(MLPack a) {
  if (blockIdx.y == 0)      mlp1_body<3>(a.j[0].x, a.j[0].w1, a.j[0].b1, a.j[0].o, a.j[0].n);
  else if (blockIdx.y == 1) mlp1_body<2>(a.j[1].x, a.j[1].w1, a.j[1].b1, a.j[1].o, a.j[1].n);
  else                      mlp1_body<16>(a.j[2].x, a.j[2].w1, a.j[2].b1, a.j[2].o, a.j[2].n);
}

// ---------------- CSR build: two-level counting sort (packed entries) --------
struct EIPack {
  const int* e0; const int* e1; const int* e2; const int* e3;
  const int* e4; const int* e5; const int* e6; const int* e7;
  int b0, b1, b2, b3, b4, b5, b6, b7;
};

__device__ __forceinline__ void ei_sel(const EIPack& t, int r, const int*& ei, int& b) {
  switch (r) {
    case 0: ei = t.e0; b = t.b0; break;
    case 1: ei = t.e1; b = t.b1; break;
    case 2: ei = t.e2; b = t.b2; break;
    case 3: ei = t.e3; b = t.b3; break;
    case 4: ei = t.e4; b = t.b4; break;
    case 5: ei = t.e5; b = t.b5; break;
    case 6: ei = t.e6; b = t.b6; break;
    default: ei = t.e7; b = t.b7; break;
  }
}

__device__ __forceinline__ int rel_shift(int rel) {
  return rel < 3 ? 12 : (rel < 6 ? 10 : 11);  // P:4096, F:1024, E:2048 dsts/bucket
}

__global__ __launch_bounds__(256) void binA1_kernel(EIPack t, int* __restrict__ counts,
                                                    int E, int nblk) {
  __shared__ int hist[NBUCK];
  int rel = blockIdx.x % 8, blk = blockIdx.x / 8;
  const int* ei; int bb;
  ei_sel(t, rel, ei, bb);
  int shift = rel_shift(rel);
  for (int i = threadIdx.x; i < NBUCK; i += 256) hist[i] = 0;
  __syncthreads();
  int e0 = blk * ABLK;
  for (int i = threadIdx.x; i < ABLK; i += 256) {
    int e = e0 + i;
    if (e < E) {
      int d = __builtin_nontemporal_load(ei + E + e);
      atomicAdd(&hist[d >> shift], 1);
    }
  }
  __syncthreads();
  for (int i = threadIdx.x; i < NBUCK; i += 256)
    counts[(rel * NBUCK + i) * nblk + blk] = hist[i];
}

__global__ __launch_bounds__(256) void binA2_kernel(EIPack t, const int* __restrict__ coff,
                                                    int* __restrict__ bed,
                                                    int E, int nblk) {
  __shared__ int cur[NBUCK];
  int rel = blockIdx.x % 8, blk = blockIdx.x / 8;
  const int* ei; int bb;
  ei_sel(t, rel, ei, bb);
  int shift = rel_shift(rel);
  int lmask = (1 << shift) - 1;
  for (int i = threadIdx.x; i < NBUCK; i += 256)
    cur[i] = coff[(rel * NBUCK + i) * nblk + blk];
  __syncthreads();
  int e0 = blk * ABLK;
  for (int i = threadIdx.x; i < ABLK; i += 256) {
    int e = e0 + i;
    if (e < E) {
      int s = __builtin_nontemporal_load(ei + e);
      int d = __builtin_nontemporal_load(ei + E + e);
      int p = atomicAdd(&cur[d >> shift], 1);
      bed[p] = ((d & lmask) << 18) | s;
    }
  }
}

__global__ __launch_bounds__(256) void binB_kernel(const int* __restrict__ coff,
                                                   const int* __restrict__ bed,
                                                   int* __restrict__ off,
                                                   int* __restrict__ srcs,
                                                   int nblk, int NP_, int NF_, int NE_,
                                                   int Etot) {
  __shared__ int hist[4096];
  __shared__ int wsum[4];
  int gb = blockIdx.x;                    // 0..8*NBUCK-1
  int rel = gb / NBUCK, b = gb % NBUCK;
  int shift = rel_shift(rel);
  int D = 1 << shift;
  int ndst_r = rel < 3 ? NP_ : (rel < 6 ? NF_ : NE_);
  int rbase = rel < 3 ? rel * NP_
            : (rel < 6 ? 3 * NP_ + (rel - 3) * NF_
                       : 3 * NP_ + 3 * NF_ + (rel - 6) * NE_);
  int d0 = b << shift;
  int Dl = min(D, ndst_r - d0);
  int ebase = coff[gb * nblk];
  int eend  = coff[(gb + 1) * nblk];
  for (int i = threadIdx.x; i < D; i += 256) hist[i] = 0;
  __syncthreads();
  for (int e = ebase + threadIdx.x; e < eend; e += 256)
    atomicAdd(&hist[bed[e] >> 18], 1);
  __syncthreads();
  const int PT = D >> 8;
  int tbase = threadIdx.x * PT;
  int ts = 0;
  for (int k = 0; k < PT; ++k) ts += hist[tbase + k];
  int lane = threadIdx.x & 63, w = threadIdx.x >> 6;
  int x = ts;
#pragma unroll
  for (int dd = 1; dd < 64; dd <<= 1) {
    int y = __shfl_up(x, dd, 64);
    if (lane >= dd) x += y;
  }
  if (lane == 63) wsum[w] = x;
  __syncthreads();
  int woff = 0;
#pragma unroll
  for (int k = 0; k < 4; ++k)
    if (k < w) woff += wsum[k];
  int pos = woff + x - ts;
  for (int k = 0; k < PT; ++k) {
    int c = hist[tbase + k];
    hist[tbase + k] = pos;
    if (tbase + k < Dl) off[rbase + d0 + tbase + k] = ebase + pos;
    pos += c;
  }
  __syncthreads();
  for (int e = ebase + threadIdx.x; e < eend; e += 256) {
    int w_ = bed[e];
    int p = atomicAdd(&hist[w_ >> 18], 1);
    srcs[ebase + p] = w_ & 0x3FFFF;
  }
  if (gb == 0 && threadIdx.x == 0)
    off[3 * NP_ + 3 * NF_ + 2 * NE_] = Etot;
}

__global__ __launch_bounds__(256) void scan1_kernel(const int* __restrict__ cnt,
                                                    int* __restrict__ part, int n) {
  __shared__ int wt[4];
  int base = blockIdx.x * 1024;
  int t = 0;
  for (int i = threadIdx.x; i < 1024; i += 256) {
    int idx = base + i;
    if (idx < n) t += cnt[idx];
  }
#pragma unroll
  for (int d = 32; d > 0; d >>= 1) t += __shfl_xor(t, d, 64);
  if ((threadIdx.x & 63) == 0) wt[threadIdx.x >> 6] = t;
  __syncthreads();
  if (threadIdx.x == 0) part[blockIdx.x] = wt[0] + wt[1] + wt[2] + wt[3];
}

__global__ __launch_bounds__(1024) void scan2_kernel(int* __restrict__ part,
                                                     int* __restrict__ off, int nb,
                                                     int n, int total) {
  __shared__ int lds[1024];
  int tid = threadIdx.x;
  int v = (tid < nb) ? part[tid] : 0;
  lds[tid] = v;
  __syncthreads();
  for (int d = 1; d < 1024; d <<= 1) {
    int y = (tid >= d) ? lds[tid - d] : 0;
    __syncthreads();
    lds[tid] += y;
    __syncthreads();
  }
  if (tid < nb) part[tid] = lds[tid] - v;  // exclusive
  if (tid == 0) off[n] = total;
}

__global__ __launch_bounds__(256) void scan3_kernel(const int* cnt,
                                                    const int* __restrict__ part,
                                                    int* __restrict__ out, int n) {
  __shared__ int wt[4];
  int base = blockIdx.x * 1024 + threadIdx.x * 4;
  int c[4];
#pragma unroll
  for (int k = 0; k < 4; ++k) {
    int idx = base + k;
    c[k] = (idx < n) ? cnt[idx] : 0;
  }
  int t = c[0] + c[1] + c[2] + c[3];
  int lane = threadIdx.x & 63, w = threadIdx.x >> 6;
  int x = t;
#pragma unroll
  for (int d = 1; d < 64; d <<= 1) {
    int y = __shfl_up(x, d, 64);
    if (lane >= d) x += y;
  }
  int ex = x - t;
  if (lane == 63) wt[w] = x;
  __syncthreads();
  int woff = 0;
#pragma unroll
  for (int k = 0; k < 4; ++k)
    if (k < w) woff += wt[k];
  int pos = part[blockIdx.x] + woff + ex;
#pragma unroll
  for (int k = 0; k < 4; ++k) {
    int idx = base + k;
    if (idx < n) out[idx] = pos;
    pos += c[k];
  }
}

// ---- mean_kernel: 8-lane group per (dst,relation); gather h rows -> mg ------
struct MPack {
  const ushort* s0; const ushort* s1; const ushort* s2; const ushort* s3;
  const ushort* s4; const ushort* s5; const ushort* s6; const ushort* s7;
  int o0, o1, o2, o3, o4, o5, o6, o7;     // off/mg row base per relation
  int n0, n1, n2, n3, n4, n5, n6, n7;     // ndst per relation
};

__global__ __launch_bounds__(256) void mean_kernel(MPack pk, const int* __restrict__ srcs,
                                                   const int* __restrict__ off,
                                                   ushort* __restrict__ mg) {
  const ushort* g; int ob, nd;
  switch (blockIdx.y) {
    case 0: g = pk.s0; ob = pk.o0; nd = pk.n0; break;
    case 1: g = pk.s1; ob = pk.o1; nd = pk.n1; break;
    case 2: g = pk.s2; ob = pk.o2; nd = pk.n2; break;
    case 3: g = pk.s3; ob = pk.o3; nd = pk.n3; break;
    case 4: g = pk.s4; ob = pk.o4; nd = pk.n4; break;
    case 5: g = pk.s5; ob = pk.o5; nd = pk.n5; break;
    case 6: g = pk.s6; ob = pk.o6; nd = pk.n6; break;
    default: g = pk.s7; ob = pk.o7; nd = pk.n7; break;
  }
  const int l8 = threadIdx.x & 7;
  const int d = (blockIdx.x * blockDim.x + threadIdx.x) >> 3;
  if (d >= nd) return;
  int e0 = off[ob + d], e1 = off[ob + d + 1];
  float t8[8];
#pragma unroll
  for (int c = 0; c < 8; ++c) t8[c] = 0.f;
  int j = e0;
  for (; j + 2 <= e1; j += 2) {
    int s0 = srcs[j], s1 = srcs[j + 1];
    bf8_t v0 = *(const bf8_t*)(g + (size_t)s0 * 64 + l8 * 8);
    bf8_t v1 = *(const bf8_t*)(g + (size_t)s1 * 64 + l8 * 8);
#pragma unroll
    for (int c = 0; c < 8; ++c) t8[c] += u2f((ushort)v0[c]) + u2f((ushort)v1[c]);
  }
  if (j < e1) {
    int s = srcs[j];
    bf8_t v = *(const bf8_t*)(g + (size_t)s * 64 + l8 * 8);
#pragma unroll
    for (int c = 0; c < 8; ++c) t8[c] += u2f((ushort)v[c]);
  }
  float inv = 1.f / fmaxf((float)(e1 - e0), 1.f);
  bf8_t outv;
#pragma unroll
  for (int c = 0; c < 8; ++c) outv[c] = (short)f2bf(t8[c] * inv);
  *(bf8_t*)(mg + (size_t)(ob + d) * 64 + l8 * 8) = outv;
}

// ---- gemmln: K=256 MFMA over [mean_a|mean_b|mean_c|h], + ReLU/res/LN --------
struct GLType {
  const ushort* hd;  ushort* hn;  const ushort* ws;
  const float* bls; const float* lng; const float* lnb;
  int b0, b1, b2, nrel, ndst;
};
struct GLPack { GLType t[3]; };

__global__ __launch_bounds__(256) void gemmln_kernel(GLPack pk, const ushort* __restrict__ mg) {
  GLType ty = (blockIdx.y == 0) ? pk.t[0] : (blockIdx.y == 1) ? pk.t[1] : pk.t[2];
  const int n = ty.ndst;
  const int lane = threadIdx.x & 63;
  const int wid = (blockIdx.x * blockDim.x + threadIdx.x) >> 6;
  const int r0 = wid * 32;
  if (r0 >= n) return;
  const int koff = ((lane >> 4) << 3);
  int ra = min(r0 + (lane & 15), n - 1);
  int rb = min(ra + 16, n - 1);
  const ushort* mA = mg + (size_t)ty.b0 * 64;
  const ushort* mB = mg + (size_t)ty.b1 * 64;
  const ushort* mC = mg + (size_t)ty.b2 * 64;
  f32x4 acc[8];
#pragma unroll
  for (int i = 0; i < 8; ++i) acc[i] = (f32x4){0.f, 0.f, 0.f, 0.f};
#pragma unroll
  for (int ks = 0; ks < 8; ++ks) {
    const ushort* bp = (ks < 2) ? mA : (ks < 4) ? mB : (ks < 6) ? mC : ty.hd;
    if (ks >= 4 && ks < 6 && ty.nrel <= 2) continue;
    int co = (ks & 1) * 32 + koff;
    bf8_t a0 = *(const bf8_t*)(bp + (size_t)ra * 64 + co);
    bf8_t a1 = *(const bf8_t*)(bp + (size_t)rb * 64 + co);
#pragma unroll
    for (int ct = 0; ct < 4; ++ct) {
      bf8_t bf = *(const bf8_t*)(ty.ws + ((size_t)(ct * 8 + ks) * 64 + lane) * 8);
      acc[ct]     = __builtin_amdgcn_mfma_f32_16x16x32_bf16(a0, bf, acc[ct], 0, 0, 0);
      acc[4 + ct] = __builtin_amdgcn_mfma_f32_16x16x32_bf16(a1, bf, acc[4 + ct], 0, 0, 0);
    }
  }
  // epilogue: +bls, ReLU, residual, LN
  const int cl = lane & 15;
  float blv[4], ggv[4], bbv[4];
#pragma unroll
  for (int ct = 0; ct < 4; ++ct) {
    blv[ct] = ty.bls[ct * 16 + cl];
    ggv[ct] = ty.lng[ct * 16 + cl];
    bbv[ct] = ty.lnb[ct * 16 + cl];
  }
#pragma unroll
  for (int rt = 0; rt < 2; ++rt) {
#pragma unroll
    for (int q = 0; q < 4; ++q) {
      int d = r0 + rt * 16 + ((lane >> 4) << 2) + q;
      if (d < n) {
        float v[4];
        float s = 0.f;
#pragma unroll
        for (int ct = 0; ct < 4; ++ct) {
          float hv = u2f(ty.hd[(size_t)d * 64 + ct * 16 + cl]);
          float x = hv + fmaxf(acc[rt * 4 + ct][q] + blv[ct], 0.f);
          v[ct] = x;
          s += x;
        }
        s += __shfl_xor(s, 1, 64);
        s += __shfl_xor(s, 2, 64);
        s += __shfl_xor(s, 4, 64);
        s += __shfl_xor(s, 8, 64);
        float m = s * (1.f / 64.f);
        float vs = 0.f;
#pragma unroll
        for (int ct = 0; ct < 4; ++ct) {
          float dd = v[ct] - m;
          vs += dd * dd;
        }
        vs += __shfl_xor(vs, 1, 64);
        vs += __shfl_xor(vs, 2, 64);
        vs += __shfl_xor(vs, 4, 64);
        vs += __shfl_xor(vs, 8, 64);
        float rstd = rsqrtf(vs * (1.f / 64.f) + 1e-5f);
#pragma unroll
        for (int ct = 0; ct < 4; ++ct)
          ty.hn[(size_t)d * 64 + ct * 16 + cl] =
              f2bf((v[ct] - m) * rstd * ggv[ct] + bbv[ct]);
      }
    }
  }
}

// ---------------- pool: 256 threads, bf8 loads, wave shfl reduce -------------
struct PoolArgs {
  const ushort* h0; const ushort* h1; const ushort* h2;
  const int* b0; const int* b1; const int* b2;
  int n0, n1, n2;
};

__global__ __launch_bounds__(256) void pool_kernel(PoolArgs a, float* __restrict__ out) {
  int ty = blockIdx.y;
  const ushort* h = (ty == 0) ? a.h0 : (ty == 1) ? a.h1 : a.h2;
  const int* batch = (ty == 0) ? a.b0 : (ty == 1) ? a.b1 : a.b2;
  int n = (ty == 0) ? a.n0 : (ty == 1) ? a.n1 : a.n2;
  int col_base = ty * 64;
  int gph = blockIdx.x >> 2;             // POOL_SPLIT = 4
  int s = blockIdx.x & 3;
  int lo = 0, hi = n;
  while (lo < hi) { int mid = (lo + hi) >> 1; if (batch[mid] < gph) lo = mid + 1; else hi = mid; }
  int beg = lo;
  hi = n;
  while (lo < hi) { int mid = (lo + hi) >> 1; if (batch[mid] < gph + 1) lo = mid + 1; else hi = mid; }
  int end = lo;
  int cnt = end - beg;
  if (cnt <= 0) return;
  int per = (cnt + POOL_SPLIT - 1) >> 2;
  int rb = beg + s * per;
  int re = min(rb + per, end);
  if (rb >= re) return;
  const int l8 = threadIdx.x & 7;
  const int grp = threadIdx.x >> 3;
  float o[8];
#pragma unroll
  for (int c = 0; c < 8; ++c) o[c] = 0.f;
  for (int r = rb + grp; r < re; r += 32) {
    bf8_t v = *(const bf8_t*)(h + (size_t)r * 64 + l8 * 8);
#pragma unroll
    for (int c = 0; c < 8; ++c) o[c] += u2f((ushort)v[c]);
  }
#pragma unroll
  for (int c = 0; c < 8; ++c) {
    o[c] += __shfl_xor(o[c], 8, 64);
    o[c] += __shfl_xor(o[c], 16, 64);
    o[c] += __shfl_xor(o[c], 32, 64);
  }
  if ((threadIdx.x & 56) == 0) {
#pragma unroll
    for (int c = 0; c < 8; ++c)
      unsafeAtomicAdd(out + gph * 192 + col_base + l8 * 8 + c, o[c]);
  }
}

__global__ __launch_bounds__(256) void pool_scale_kernel(
    float* __restrict__ out, const int* __restrict__ bp,
    const int* __restrict__ be, const int* __restrict__ bf,
    int np, int ne, int nf) {
  int idx = blockIdx.x * blockDim.x + threadIdx.x;
  if (idx >= 64 * 192) return;
  int gph = idx / 192, col = idx % 192;
  const int* b;
  int n;
  if (col < 64) { b = bp; n = np; }
  else if (col < 128) { b = be; n = ne; }
  else { b = bf; n = nf; }
  int lo = 0, hi = n;
  while (lo < hi) { int mid = (lo + hi) >> 1; if (b[mid] < gph) lo = mid + 1; else hi = mid; }
  int beg = lo;
  hi = n;
  while (lo < hi) { int mid = (lo + hi) >> 1; if (b[mid] < gph + 1) lo = mid + 1; else hi = mid; }
  int cnt = lo - beg;
  out[idx] = out[idx] / fmaxf((float)cnt, 1.f);
}

extern "C" void kernel_launch(void* const* d_in, const int* in_sizes, int n_in,
                              void* d_out, int out_size, void* d_ws, size_t ws_size,
                              hipStream_t stream) {
  const float* point_x = (const float*)d_in[0];
  const float* edge_x  = (const float*)d_in[1];
  const float* face_x  = (const float*)d_in[2];
  const int* bp = (const int*)d_in[3];
  const int* be = (const int*)d_in[4];
  const int* bf = (const int*)d_in[5];
  const int NP = in_sizes[3], NE = in_sizes[4], NF = in_sizes[5];
  const int Eg = in_sizes[6] / 2;

  const float* Wl  = (const float*)d_in[26];
  const float* blp = (const float*)d_in[27];
  const float* Wr  = (const float*)d_in[28];
  const float* lng = (const float*)d_in[29];
  const float* lnb = (const float*)d_in[30];

  // relations: 0 pp 1 fp 2 ep (dst P) | 3 pf 4 ef 5 ff (dst F) | 6 pe 7 fe (dst E)
  int ndst[8] = {NP, NP, NP, NF, NF, NF, NE, NE};
  int base[8];
  base[0] = 0;
  for (int r = 1; r < 8; ++r) base[r] = base[r - 1] + ndst[r - 1];
  const int NDSUM = 3 * NP + 3 * NF + 2 * NE;

  // ---- workspace layout (~232 MB) ----
  char* p = (char*)d_ws;
  ushort* hA = (ushort*)p; p += (size_t)(NP + NE + NF) * 64 * 2;   // 44.8 MB
  ushort* hB = (ushort*)p; p += (size_t)(NP + NE + NF) * 64 * 2;   // 44.8 MB
  ushort* mg = (ushort*)p; p += (size_t)NDSUM * 64 * 2;            // 121.6 MB
  ushort* fw0 = (ushort*)p; p += (size_t)3 * 4096 * 2;
  float* bls = (float*)p; p += 6 * 64 * 4;
  ushort* fws = (ushort*)p; p += (size_t)6 * 16384 * 2;
  int* srcs = (int*)p; p += (size_t)8 * Eg * 4;                     // 16 MB
  int* off = (int*)p; p += (size_t)(NDSUM + 1) * 4;
  const int nblk = (Eg + ABLK - 1) / ABLK;
  const int NCNT = 8 * NBUCK * nblk;
  int* counts = (int*)p; p += (size_t)NCNT * 4;
  int* coff = (int*)p; p += (size_t)(NCNT + 1) * 4;
  int* part = (int*)p; p += 4096;
  int* bed = (int*)mg;   // 16 MB alias; CSR build completes before mg is written

  ushort* h_[2][3];
  h_[0][0] = hA; h_[0][1] = hA + (size_t)NP * 64; h_[0][2] = hA + (size_t)(NP + NE) * 64;
  h_[1][0] = hB; h_[1][1] = hB + (size_t)NP * 64; h_[1][2] = hB + (size_t)(NP + NE) * 64;

  const int* ei[8] = {(const int*)d_in[6],  (const int*)d_in[7],
                      (const int*)d_in[8],  (const int*)d_in[9],
                      (const int*)d_in[10], (const int*)d_in[11],
                      (const int*)d_in[12], (const int*)d_in[13]};
  EIPack ep;
  ep.e0 = ei[0]; ep.e1 = ei[1]; ep.e2 = ei[2]; ep.e3 = ei[3];
  ep.e4 = ei[4]; ep.e5 = ei[5]; ep.e6 = ei[6]; ep.e7 = ei[7];
  ep.b0 = base[0]; ep.b1 = base[1]; ep.b2 = base[2]; ep.b3 = base[3];
  ep.b4 = base[4]; ep.b5 = base[5]; ep.b6 = base[6]; ep.b7 = base[7];

  // ---- CSR build (bed aliases mg; done before any mean_kernel) ----
  binA1_kernel<<<8 * nblk, 256, 0, stream>>>(ep, counts, Eg, nblk);
  const int nb = (NCNT + 1023) / 1024;
  scan1_kernel<<<nb, 256, 0, stream>>>(counts, part, NCNT);
  scan2_kernel<<<1, 1024, 0, stream>>>(part, coff, nb, NCNT, 8 * Eg);
  scan3_kernel<<<nb, 256, 0, stream>>>(counts, part, coff, NCNT);
  binA2_kernel<<<8 * nblk, 256, 0, stream>>>(ep, coff, bed, Eg, nblk);
  binB_kernel<<<8 * NBUCK, 256, 0, stream>>>(coff, bed, off, srcs,
                                             nblk, NP, NF, NE, 8 * Eg);

  // ---- weight prep ----
  prep_kernel<<<(3 * 4096 + 6 * 64 + 6 * 16384 + 255) / 256, 256, 0, stream>>>(
      Wl, Wr, blp, (const float*)d_in[16], (const float*)d_in[20],
      (const float*)d_in[24], fw0, bls, fws);

  // ---- input MLPs: stage1 into hB scratch, stage2 K=64 MFMA -> hA ----
  MLPack ma;
  ma.j[0] = {point_x, (const float*)d_in[14], (const float*)d_in[15], h_[1][0], NP};
  ma.j[1] = {edge_x,  (const float*)d_in[18], (const float*)d_in[19], h_[1][1], NE};
  ma.j[2] = {face_x,  (const float*)d_in[22], (const float*)d_in[23], h_[1][2], NF};
  mlp1_kernel<<<dim3(512, 3), 256, 0, stream>>>(ma);

  GJobs3 init;
  init.j0 = {h_[1][0], fw0 + 0 * 4096, (const float*)d_in[17], h_[0][0], NP};
  init.j1 = {h_[1][1], fw0 + 1 * 4096, (const float*)d_in[21], h_[0][1], NE};
  init.j2 = {h_[1][2], fw0 + 2 * 4096, (const float*)d_in[25], h_[0][2], NF};
  gemm3_kernel<<<dim3(((NP + 31) / 32 + 3) / 4, 3), 256, 0, stream>>>(init);

  // ---- 2 hetero-SAGE layers: mean dispatch + gemmln dispatch each ----
  const int mnx = (NP * 8 + 255) / 256;
  const int glx = ((NP + 31) / 32 + 3) / 4;
  int cs = 0;
  for (int i = 0; i < 2; ++i) {
    int ns = cs ^ 1;
    ushort* hp_ = h_[cs][0];
    ushort* he_ = h_[cs][1];
    ushort* hf_ = h_[cs][2];
    // gather sources per relation: pp fp ep pf ef ff pe fe
    MPack mp;
    mp.s0 = hp_; mp.s1 = hf_; mp.s2 = he_; mp.s3 = hp_;
    mp.s4 = he_; mp.s5 = hf_; mp.s6 = hp_; mp.s7 = hf_;
    mp.o0 = base[0]; mp.o1 = base[1]; mp.o2 = base[2]; mp.o3 = base[3];
    mp.o4 = base[4]; mp.o5 = base[5]; mp.o6 = base[6]; mp.o7 = base[7];
    mp.n0 = ndst[0]; mp.n1 = ndst[1]; mp.n2 = ndst[2]; mp.n3 = ndst[3];
    mp.n4 = ndst[4]; mp.n5 = ndst[5]; mp.n6 = ndst[6]; mp.n7 = ndst[7];
    mean_kernel<<<dim3(mnx, 8), 256, 0, stream>>>(mp, srcs, off, mg);

    GLPack pk;
    // P (t=0): rels 0,1,2
    pk.t[0] = {hp_, h_[ns][0], fws + (size_t)(i * 3 + 0) * 16384,
               bls + (i * 3 + 0) * 64, lng + (i * 3 + 0) * 64, lnb + (i * 3 + 0) * 64,
               base[0], base[1], base[2], 3, NP};
    // F (t=2): rels 3,4,5
    pk.t[1] = {hf_, h_[ns][2], fws + (size_t)(i * 3 + 2) * 16384,
               bls + (i * 3 + 2) * 64, lng + (i * 3 + 2) * 64, lnb + (i * 3 + 2) * 64,
               base[3], base[4], base[5], 3, NF};
    // E (t=1): rels 6,7 (section c skipped via nrel)
    pk.t[2] = {he_, h_[ns][1], fws + (size_t)(i * 3 + 1) * 16384,
               bls + (i * 3 + 1) * 64, lng + (i * 3 + 1) * 64, lnb + (i * 3 + 1) * 64,
               base[6], base[7], 0, 2, NE};
    gemmln_kernel<<<dim3(glx, 3), 256, 0, stream>>>(pk, mg);
    cs = ns;
  }

  // ---- pool + scale ----
  float* out = (float*)d_out;
  hipMemsetAsync(out, 0, (size_t)out_size * sizeof(float), stream);
  PoolArgs pa;
  pa.h0 = h_[cs][0]; pa.h1 = h_[cs][1]; pa.h2 = h_[cs][2];
  pa.b0 = bp; pa.b1 = be; pa.b2 = bf;
  pa.n0 = NP; pa.n1 = NE; pa.n2 = NF;
  pool_kernel<<<dim3(64 * POOL_SPLIT, 3), 256, 0, stream>>>(pa, out);
  pool_scale_kernel<<<(64 * 192 + 255) / 256, 256, 0, stream>>>(out, bp, be, bf, NP, NE, NF);
}